// Round 1
// baseline (2727.669 us; speedup 1.0000x reference)
//
#include <hip/hip_runtime.h>
#include <cstdint>

#define NN 100000
#define NE 3200000
#define DD 128

// One wave (64 lanes) per edge; each lane handles 2 of the 128 features.
// agg[r*128 + d] += w * x[c*128 + d] via f32 atomics.
__global__ __launch_bounds__(256) void scatter_k(
    const float* __restrict__ x, const float* __restrict__ ew,
    const int* __restrict__ rows, const int* __restrict__ cols,
    float* __restrict__ agg)
{
    int e    = blockIdx.x * 4 + (threadIdx.x >> 6);   // NE % 4 == 0, no guard
    int lane = threadIdx.x & 63;
    int r = rows[e];
    int c = cols[e];
    float w = ew[e];
    float2 v = reinterpret_cast<const float2*>(x + (size_t)c * DD)[lane];
    float* ag = agg + (size_t)r * DD + lane * 2;
    atomicAdd(ag,     w * v.x);
    atomicAdd(ag + 1, w * v.y);
}

// out[n][o] = tanh( sum_k agg[n][k] * W[o][k] )
// 256 threads/block, 32 rows/block (100000 % 32 == 0 -> 3125 blocks).
// In-place safe: each block stages its own 32 agg rows to LDS, syncs,
// then overwrites exactly those rows.
__global__ __launch_bounds__(256) void gemm_tanh_k(
    const float* __restrict__ agg, const float* __restrict__ W,
    float* __restrict__ out)
{
    __shared__ float Wt[DD][DD + 4];   // Wt[k][o] = W[o][k]; stride 132*4=528B keeps 16B align
    __shared__ float At[32][DD];       // 32-row agg tile

    int tid = threadIdx.x;

    // Stage W transposed (coalesced read, scattered LDS write — once per block)
    for (int i = tid; i < DD * DD; i += 256) {
        int o = i >> 7, k = i & 127;
        Wt[k][o] = W[i];
    }
    int row0 = blockIdx.x * 32;
    // Stage agg tile (coalesced)
    for (int i = tid; i < 32 * DD; i += 256) {
        At[i >> 7][i & 127] = agg[(size_t)row0 * DD + i];
    }
    __syncthreads();

    int colg = tid & 31;     // 32 col-groups * 4 cols = 128
    int rowg = tid >> 5;     // 8 row-groups  * 4 rows = 32
    int c0 = colg * 4;
    int r0 = rowg * 4;

    float acc[4][4] = {};
    for (int k = 0; k < DD; ++k) {
        float4 wv = *reinterpret_cast<const float4*>(&Wt[k][c0]);
        #pragma unroll
        for (int i = 0; i < 4; ++i) {
            float a = At[r0 + i][k];
            acc[i][0] += a * wv.x;
            acc[i][1] += a * wv.y;
            acc[i][2] += a * wv.z;
            acc[i][3] += a * wv.w;
        }
    }

    #pragma unroll
    for (int i = 0; i < 4; ++i) {
        int r = row0 + r0 + i;
        float4 o4 = { tanhf(acc[i][0]), tanhf(acc[i][1]),
                      tanhf(acc[i][2]), tanhf(acc[i][3]) };
        *reinterpret_cast<float4*>(&out[(size_t)r * DD + c0]) = o4;
    }
}

extern "C" void kernel_launch(void* const* d_in, const int* in_sizes, int n_in,
                              void* d_out, int out_size, void* d_ws, size_t ws_size,
                              hipStream_t stream) {
    const float* x  = (const float*)d_in[0];   // [NN, 128]
    const float* W  = (const float*)d_in[1];   // [128, 128]
    const float* ew = (const float*)d_in[2];   // [NE]
    const int*   ei = (const int*)d_in[3];     // [2, NE]
    const int* rows = ei;
    const int* cols = ei + NE;
    float* out = (float*)d_out;                // [NN, 128] f32; doubles as agg buffer

    hipMemsetAsync(out, 0, (size_t)NN * DD * sizeof(float), stream);
    scatter_k<<<NE / 4, 256, 0, stream>>>(x, ew, rows, cols, out);
    gemm_tanh_k<<<NN / 32, 256, 0, stream>>>(out, W, out);
}

// Round 2
// 720.955 us; speedup vs baseline: 3.7834x; 3.7834x over previous
//
#include <hip/hip_runtime.h>
#include <cstdint>

#define NN 100000
#define NE 3200000
#define DD 128

#define SCAN_T 256
#define SCAN_I 4
#define SCAN_B (SCAN_T * SCAN_I)            // 1024 items per scan block
#define NBLK ((NN + SCAN_B - 1) / SCAN_B)   // 98

// ---------------- CSR build ----------------

__global__ __launch_bounds__(256) void hist_k(
    const int* __restrict__ rows, int* __restrict__ counts)
{
    int e = blockIdx.x * 256 + threadIdx.x;   // NE % 256 == 0
    atomicAdd(&counts[rows[e]], 1);
}

__global__ __launch_bounds__(256) void scan_reduce_k(
    const int* __restrict__ counts, int* __restrict__ blocksums)
{
    __shared__ int sd[SCAN_T];
    int b = blockIdx.x, t = threadIdx.x;
    int base = b * SCAN_B + t * SCAN_I;
    int s = 0;
    #pragma unroll
    for (int i = 0; i < SCAN_I; ++i) {
        int idx = base + i;
        if (idx < NN) s += counts[idx];
    }
    sd[t] = s; __syncthreads();
    for (int off = SCAN_T / 2; off > 0; off >>= 1) {
        if (t < off) sd[t] += sd[t + off];
        __syncthreads();
    }
    if (t == 0) blocksums[b] = sd[0];
}

__global__ __launch_bounds__(128) void scan_tops_k(int* __restrict__ blocksums)
{
    __shared__ int sd[128];
    int t = threadIdx.x;
    int v = (t < NBLK) ? blocksums[t] : 0;
    sd[t] = v; __syncthreads();
    for (int off = 1; off < 128; off <<= 1) {
        int add = (t >= off) ? sd[t - off] : 0;
        __syncthreads();
        sd[t] += add;
        __syncthreads();
    }
    if (t < NBLK) blocksums[t] = sd[t] - v;   // exclusive
}

__global__ __launch_bounds__(256) void scan_down_k(
    const int* __restrict__ counts, const int* __restrict__ blocksums,
    int* __restrict__ offsets, int* __restrict__ cursors)
{
    __shared__ int sd[SCAN_T];
    int b = blockIdx.x, t = threadIdx.x;
    int base = b * SCAN_B + t * SCAN_I;
    int v[SCAN_I]; int s = 0;
    #pragma unroll
    for (int i = 0; i < SCAN_I; ++i) {
        int idx = base + i;
        v[i] = (idx < NN) ? counts[idx] : 0;
        s += v[i];
    }
    sd[t] = s; __syncthreads();
    for (int off = 1; off < SCAN_T; off <<= 1) {
        int add = (t >= off) ? sd[t - off] : 0;
        __syncthreads();
        sd[t] += add;
        __syncthreads();
    }
    int excl = sd[t] - s + blocksums[b];
    #pragma unroll
    for (int i = 0; i < SCAN_I; ++i) {
        int idx = base + i;
        if (idx < NN) { offsets[idx] = excl; cursors[idx] = excl; }
        excl += v[i];
    }
}

__global__ __launch_bounds__(256) void bucket_k(
    const int* __restrict__ rows, const int* __restrict__ cols,
    const float* __restrict__ ew, int* __restrict__ cursors,
    uint2* __restrict__ bucket)
{
    int e = blockIdx.x * 256 + threadIdx.x;   // NE % 256 == 0
    int r = rows[e];
    int pos = atomicAdd(&cursors[r], 1);
    uint2 ent;
    ent.x = (unsigned)cols[e];
    ent.y = __float_as_uint(ew[e]);
    bucket[pos] = ent;
}

// ---------------- gather (atomic-free SpMM) ----------------
// One wave per node; lane owns features [2*lane, 2*lane+1].
__global__ __launch_bounds__(256) void gather_k(
    const float* __restrict__ x, const uint2* __restrict__ bucket,
    const int* __restrict__ offsets, const int* __restrict__ counts,
    float* __restrict__ agg)
{
    int node = blockIdx.x * 4 + (threadIdx.x >> 6);   // NN % 4 == 0
    int lane = threadIdx.x & 63;
    int start = offsets[node];
    int cnt   = counts[node];
    const float2* x2 = reinterpret_cast<const float2*>(x);

    float2 acc = {0.f, 0.f};
    int i = 0;
    for (; i + 1 < cnt; i += 2) {
        uint2 e0 = bucket[start + i];
        uint2 e1 = bucket[start + i + 1];
        float2 v0 = x2[(size_t)e0.x * 64 + lane];
        float2 v1 = x2[(size_t)e1.x * 64 + lane];
        float w0 = __uint_as_float(e0.y);
        float w1 = __uint_as_float(e1.y);
        acc.x += w0 * v0.x;
        acc.y += w0 * v0.y;
        acc.x += w1 * v1.x;
        acc.y += w1 * v1.y;
    }
    if (i < cnt) {
        uint2 e0 = bucket[start + i];
        float2 v0 = x2[(size_t)e0.x * 64 + lane];
        float w0 = __uint_as_float(e0.y);
        acc.x += w0 * v0.x;
        acc.y += w0 * v0.y;
    }
    reinterpret_cast<float2*>(agg + (size_t)node * DD)[lane] = acc;
}

// ---------------- fallback scatter (if ws too small) ----------------
__global__ __launch_bounds__(256) void scatter_k(
    const float* __restrict__ x, const float* __restrict__ ew,
    const int* __restrict__ rows, const int* __restrict__ cols,
    float* __restrict__ agg)
{
    int e    = blockIdx.x * 4 + (threadIdx.x >> 6);
    int lane = threadIdx.x & 63;
    int r = rows[e];
    int c = cols[e];
    float w = ew[e];
    float2 v = reinterpret_cast<const float2*>(x + (size_t)c * DD)[lane];
    float* ag = agg + (size_t)r * DD + lane * 2;
    atomicAdd(ag,     w * v.x);
    atomicAdd(ag + 1, w * v.y);
}

// ---------------- GEMM + tanh (in-place, unchanged) ----------------
__global__ __launch_bounds__(256) void gemm_tanh_k(
    const float* __restrict__ agg, const float* __restrict__ W,
    float* __restrict__ out)
{
    __shared__ float Wt[DD][DD + 4];
    __shared__ float At[32][DD];

    int tid = threadIdx.x;
    for (int i = tid; i < DD * DD; i += 256) {
        int o = i >> 7, k = i & 127;
        Wt[k][o] = W[i];
    }
    int row0 = blockIdx.x * 32;
    for (int i = tid; i < 32 * DD; i += 256) {
        At[i >> 7][i & 127] = agg[(size_t)row0 * DD + i];
    }
    __syncthreads();

    int colg = tid & 31;
    int rowg = tid >> 5;
    int c0 = colg * 4;
    int r0 = rowg * 4;

    float acc[4][4] = {};
    for (int k = 0; k < DD; ++k) {
        float4 wv = *reinterpret_cast<const float4*>(&Wt[k][c0]);
        #pragma unroll
        for (int i = 0; i < 4; ++i) {
            float a = At[r0 + i][k];
            acc[i][0] += a * wv.x;
            acc[i][1] += a * wv.y;
            acc[i][2] += a * wv.z;
            acc[i][3] += a * wv.w;
        }
    }

    #pragma unroll
    for (int i = 0; i < 4; ++i) {
        int r = row0 + r0 + i;
        float4 o4 = { tanhf(acc[i][0]), tanhf(acc[i][1]),
                      tanhf(acc[i][2]), tanhf(acc[i][3]) };
        *reinterpret_cast<float4*>(&out[(size_t)r * DD + c0]) = o4;
    }
}

extern "C" void kernel_launch(void* const* d_in, const int* in_sizes, int n_in,
                              void* d_out, int out_size, void* d_ws, size_t ws_size,
                              hipStream_t stream) {
    const float* x  = (const float*)d_in[0];
    const float* W  = (const float*)d_in[1];
    const float* ew = (const float*)d_in[2];
    const int*   ei = (const int*)d_in[3];
    const int* rows = ei;
    const int* cols = ei + NE;
    float* out = (float*)d_out;   // doubles as agg buffer

    // Workspace layout
    //   counts    : NN ints
    //   offsets   : NN ints
    //   cursors   : NN ints
    //   blocksums : 128 ints
    //   bucket    : NE uint2
    size_t int_words = (size_t)3 * NN + 128;
    size_t need = int_words * sizeof(int) + (size_t)NE * sizeof(uint2);

    if (ws_size >= need) {
        int* counts    = (int*)d_ws;
        int* offsets   = counts + NN;
        int* cursors   = offsets + NN;
        int* blocksums = cursors + NN;
        uint2* bucket  = (uint2*)(blocksums + 128);

        hipMemsetAsync(counts, 0, (size_t)NN * sizeof(int), stream);
        hist_k<<<NE / 256, 256, 0, stream>>>(rows, counts);
        scan_reduce_k<<<NBLK, 256, 0, stream>>>(counts, blocksums);
        scan_tops_k<<<1, 128, 0, stream>>>(blocksums);
        scan_down_k<<<NBLK, 256, 0, stream>>>(counts, blocksums, offsets, cursors);
        bucket_k<<<NE / 256, 256, 0, stream>>>(rows, cols, ew, cursors, bucket);
        gather_k<<<NN / 4, 256, 0, stream>>>(x, bucket, offsets, counts, out);
    } else {
        hipMemsetAsync(out, 0, (size_t)NN * DD * sizeof(float), stream);
        scatter_k<<<NE / 4, 256, 0, stream>>>(x, ew, rows, cols, out);
    }
    gemm_tanh_k<<<NN / 32, 256, 0, stream>>>(out, W, out);
}